// Round 2
// baseline (187.469 us; speedup 1.0000x reference)
//
#include <hip/hip_runtime.h>

// CompositeLoss: single-pass fused masked reduction over (2,3,128,128,128).
// 13 partial sums:
//  0:M  1:Mx(d) 2:My(h) 3:Mz(w)  4:Smae 5:Smse 6:Sbg
//  7:Sgx 8:Sgy 9:Sgz  10:Stx 11:Sty 12:Stz
#define NACC 13
#define NBLOCKS 4096   // 2^20 groups / 256 threads

__device__ __forceinline__ float4 ld4(const float* p) {
    return *reinterpret_cast<const float4*>(p);
}

__global__ __launch_bounds__(256) void loss_main(
    const float* __restrict__ pred, const float* __restrict__ target,
    const float* __restrict__ mask, float* __restrict__ partials)
{
    float acc[NACC];
#pragma unroll
    for (int k = 0; k < NACC; ++k) acc[k] = 0.f;

    const float4 z4 = make_float4(0.f, 0.f, 0.f, 0.f);

    // one group per thread: group = (b, d, h, w4); 2*128*128*32 = 2^20 groups
    const int g  = blockIdx.x * 256 + threadIdx.x;
    const int w4 = g & 31;
    const int h  = (g >> 5) & 127;
    const int d  = (g >> 12) & 127;
    const int b  = g >> 19;
    const int w  = w4 << 2;
    const int mb  = b * 2097152 + d * 16384 + h * 128 + w; // mask index
    const int pb0 = b * 6291456 + d * 16384 + h * 128 + w; // pred/target base (c=0)
    const bool hw = w4 < 31, hh = h < 127, hd = d < 127;

    const float4 m0  = ld4(mask + mb);
    const float  m4w = hw ? mask[mb + 4] : 0.f;
    const float4 mh  = hh ? ld4(mask + mb + 128)   : z4;
    const float4 md  = hd ? ld4(mask + mb + 16384) : z4;

    // pairwise mins (binary mask -> AND); zero-filled neighbors kill OOB terms
    const float mz0 = fminf(m0.x, m0.y), mz1 = fminf(m0.y, m0.z),
                mz2 = fminf(m0.z, m0.w), mz3 = fminf(m0.w, m4w);
    const float my0 = fminf(m0.x, mh.x), my1 = fminf(m0.y, mh.y),
                my2 = fminf(m0.z, mh.z), my3 = fminf(m0.w, mh.w);
    const float mx0 = fminf(m0.x, md.x), mx1 = fminf(m0.y, md.y),
                mx2 = fminf(m0.z, md.z), mx3 = fminf(m0.w, md.w);

    acc[0] = m0.x + m0.y + m0.z + m0.w;
    acc[1] = mx0 + mx1 + mx2 + mx3;
    acc[2] = my0 + my1 + my2 + my3;
    acc[3] = mz0 + mz1 + mz2 + mz3;

#pragma unroll
    for (int c = 0; c < 3; ++c) {
        const int pb = pb0 + c * 2097152;
        const float4 p0 = ld4(pred + pb);
        const float4 t0 = ld4(target + pb);
        float p4 = 0.f, t4 = 0.f;
        if (hw) { p4 = pred[pb + 4]; t4 = target[pb + 4]; }
        const float4 ph = hh ? ld4(pred + pb + 128)     : z4;
        const float4 th = hh ? ld4(target + pb + 128)   : z4;
        const float4 pd = hd ? ld4(pred + pb + 16384)   : z4;
        const float4 td = hd ? ld4(target + pb + 16384) : z4;

        const float e0x = p0.x - t0.x, e0y = p0.y - t0.y,
                    e0z = p0.z - t0.z, e0w = p0.w - t0.w;
        const float e4  = p4 - t4;

        acc[4] += fabsf(e0x)*m0.x + fabsf(e0y)*m0.y
                + fabsf(e0z)*m0.z + fabsf(e0w)*m0.w;
        acc[5] += e0x*e0x*m0.x + e0y*e0y*m0.y
                + e0z*e0z*m0.z + e0w*e0w*m0.w;
        acc[6] += fabsf(p0.x)*(1.f-m0.x) + fabsf(p0.y)*(1.f-m0.y)
                + fabsf(p0.z)*(1.f-m0.z) + fabsf(p0.w)*(1.f-m0.w);

        // W direction (reference dz)
        acc[9]  += fabsf(e0y-e0x)*mz0 + fabsf(e0z-e0y)*mz1
                 + fabsf(e0w-e0z)*mz2 + fabsf(e4 -e0w)*mz3;
        acc[12] += fabsf(p0.y-p0.x)*mz0 + fabsf(p0.z-p0.y)*mz1
                 + fabsf(p0.w-p0.z)*mz2 + fabsf(p4  -p0.w)*mz3;

        // H direction (reference dy)
        const float ehx = ph.x - th.x, ehy = ph.y - th.y,
                    ehz = ph.z - th.z, ehw = ph.w - th.w;
        acc[8]  += fabsf(ehx-e0x)*my0 + fabsf(ehy-e0y)*my1
                 + fabsf(ehz-e0z)*my2 + fabsf(ehw-e0w)*my3;
        acc[11] += fabsf(ph.x-p0.x)*my0 + fabsf(ph.y-p0.y)*my1
                 + fabsf(ph.z-p0.z)*my2 + fabsf(ph.w-p0.w)*my3;

        // D direction (reference dx)
        const float edx = pd.x - td.x, edy = pd.y - td.y,
                    edz = pd.z - td.z, edw = pd.w - td.w;
        acc[7]  += fabsf(edx-e0x)*mx0 + fabsf(edy-e0y)*mx1
                 + fabsf(edz-e0z)*mx2 + fabsf(edw-e0w)*mx3;
        acc[10] += fabsf(pd.x-p0.x)*mx0 + fabsf(pd.y-p0.y)*mx1
                 + fabsf(pd.z-p0.z)*mx2 + fabsf(pd.w-p0.w)*mx3;
    }

    // wave (64) shuffle reduce -> LDS -> per-block partials (layout [k][block])
    const int lane = threadIdx.x & 63;
    const int wave = threadIdx.x >> 6;
    __shared__ float red[4][NACC];
#pragma unroll
    for (int k = 0; k < NACC; ++k) {
        float v = acc[k];
        for (int o = 32; o > 0; o >>= 1) v += __shfl_down(v, o, 64);
        if (lane == 0) red[wave][k] = v;
    }
    __syncthreads();
    if (threadIdx.x < NACC) {
        const int k = threadIdx.x;
        partials[k * NBLOCKS + blockIdx.x] =
            red[0][k] + red[1][k] + red[2][k] + red[3][k];
    }
}

__global__ __launch_bounds__(256) void loss_final(
    const float* __restrict__ partials, float* __restrict__ out)
{
    float acc[NACC];
#pragma unroll
    for (int k = 0; k < NACC; ++k) {
        float v = 0.f;
        // coalesced: thread t reads partials[k*NBLOCKS + t + 256*i]
        for (int i = threadIdx.x; i < NBLOCKS; i += 256) v += partials[k * NBLOCKS + i];
        acc[k] = v;
    }
    const int lane = threadIdx.x & 63;
    const int wave = threadIdx.x >> 6;
    __shared__ float red[4][NACC];
#pragma unroll
    for (int k = 0; k < NACC; ++k) {
        float v = acc[k];
        for (int o = 32; o > 0; o >>= 1) v += __shfl_down(v, o, 64);
        if (lane == 0) red[wave][k] = v;
    }
    __syncthreads();
    if (threadIdx.x == 0) {
        float a[NACC];
#pragma unroll
        for (int k = 0; k < NACC; ++k)
            a[k] = red[0][k] + red[1][k] + red[2][k] + red[3][k];
        const float EPS = 1e-8f;
        const float M = a[0], Mx = a[1], My = a[2], Mz = a[3];
        const float dm = 3.f * M + EPS;
        float loss = (a[4] + a[5]) / dm;  // W_MAE=1, W_MSE=1
        loss += 0.1f   * (a[7] / (3.f*Mx + EPS) + a[8] / (3.f*My + EPS)
                        + a[9] / (3.f*Mz + EPS));
        loss += 0.002f * (a[10] / (3.f*Mx + EPS) + a[11] / (3.f*My + EPS)
                        + a[12] / (3.f*Mz + EPS));
        const float inv = 4194304.f - M;  // B*D*H*W - M
        loss += 0.15f * a[6] / (3.f * inv + EPS);
        out[0] = loss;
    }
}

extern "C" void kernel_launch(void* const* d_in, const int* in_sizes, int n_in,
                              void* d_out, int out_size, void* d_ws, size_t ws_size,
                              hipStream_t stream) {
    const float* pred   = (const float*)d_in[0];
    const float* target = (const float*)d_in[1];
    const float* mask   = (const float*)d_in[2];
    float* out      = (float*)d_out;
    float* partials = (float*)d_ws;  // NACC * NBLOCKS floats = 208 KiB

    loss_main<<<NBLOCKS, 256, 0, stream>>>(pred, target, mask, partials);
    loss_final<<<1, 256, 0, stream>>>(partials, out);
}

// Round 3
// 149.163 us; speedup vs baseline: 1.2568x; 1.2568x over previous
//
#include <hip/hip_runtime.h>

// CompositeLoss: single-pass fused masked reduction over (2,3,128,128,128).
// 13 partial sums (padded to 16 per block in d_ws):
//  0:M  1:Mx(d) 2:My(h) 3:Mz(w)  4:Smae 5:Smse 6:Sbg
//  7:Sgx 8:Sgy 9:Sgz  10:Stx 11:Sty 12:Stz
#define NACC 13
#define NPAD 16
#define NBLOCKS 4096   // 2^20 groups / 256 threads

__device__ __forceinline__ float4 ld4(const float* p) {
    return *reinterpret_cast<const float4*>(p);
}

__global__ __launch_bounds__(256) void loss_main(
    const float* __restrict__ pred, const float* __restrict__ target,
    const float* __restrict__ mask, float* __restrict__ partials)
{
    float acc[NACC];
#pragma unroll
    for (int k = 0; k < NACC; ++k) acc[k] = 0.f;

    const float4 z4 = make_float4(0.f, 0.f, 0.f, 0.f);

    // one group per thread: group = (b, d, h, w4); 2*128*128*32 = 2^20 groups
    const int g  = blockIdx.x * 256 + threadIdx.x;
    const int w4 = g & 31;
    const int h  = (g >> 5) & 127;
    const int d  = (g >> 12) & 127;
    const int b  = g >> 19;
    const int w  = w4 << 2;
    const int mb  = b * 2097152 + d * 16384 + h * 128 + w; // mask index
    const int pb0 = b * 6291456 + d * 16384 + h * 128 + w; // pred/target base (c=0)
    const bool hw = w4 < 31, hh = h < 127, hd = d < 127;

    const float4 m0  = ld4(mask + mb);
    const float  m4w = hw ? mask[mb + 4] : 0.f;
    const float4 mh  = hh ? ld4(mask + mb + 128)   : z4;
    const float4 md  = hd ? ld4(mask + mb + 16384) : z4;

    // pairwise mins (binary mask -> AND); zero-filled neighbors kill OOB terms
    const float mz0 = fminf(m0.x, m0.y), mz1 = fminf(m0.y, m0.z),
                mz2 = fminf(m0.z, m0.w), mz3 = fminf(m0.w, m4w);
    const float my0 = fminf(m0.x, mh.x), my1 = fminf(m0.y, mh.y),
                my2 = fminf(m0.z, mh.z), my3 = fminf(m0.w, mh.w);
    const float mx0 = fminf(m0.x, md.x), mx1 = fminf(m0.y, md.y),
                mx2 = fminf(m0.z, md.z), mx3 = fminf(m0.w, md.w);

    acc[0] = m0.x + m0.y + m0.z + m0.w;
    acc[1] = mx0 + mx1 + mx2 + mx3;
    acc[2] = my0 + my1 + my2 + my3;
    acc[3] = mz0 + mz1 + mz2 + mz3;

#pragma unroll
    for (int c = 0; c < 3; ++c) {
        const int pb = pb0 + c * 2097152;
        const float4 p0 = ld4(pred + pb);
        const float4 t0 = ld4(target + pb);
        float p4 = 0.f, t4 = 0.f;
        if (hw) { p4 = pred[pb + 4]; t4 = target[pb + 4]; }
        const float4 ph = hh ? ld4(pred + pb + 128)     : z4;
        const float4 th = hh ? ld4(target + pb + 128)   : z4;
        const float4 pd = hd ? ld4(pred + pb + 16384)   : z4;
        const float4 td = hd ? ld4(target + pb + 16384) : z4;

        const float e0x = p0.x - t0.x, e0y = p0.y - t0.y,
                    e0z = p0.z - t0.z, e0w = p0.w - t0.w;
        const float e4  = p4 - t4;

        acc[4] += fabsf(e0x)*m0.x + fabsf(e0y)*m0.y
                + fabsf(e0z)*m0.z + fabsf(e0w)*m0.w;
        acc[5] += e0x*e0x*m0.x + e0y*e0y*m0.y
                + e0z*e0z*m0.z + e0w*e0w*m0.w;
        acc[6] += fabsf(p0.x)*(1.f-m0.x) + fabsf(p0.y)*(1.f-m0.y)
                + fabsf(p0.z)*(1.f-m0.z) + fabsf(p0.w)*(1.f-m0.w);

        // W direction (reference dz)
        acc[9]  += fabsf(e0y-e0x)*mz0 + fabsf(e0z-e0y)*mz1
                 + fabsf(e0w-e0z)*mz2 + fabsf(e4 -e0w)*mz3;
        acc[12] += fabsf(p0.y-p0.x)*mz0 + fabsf(p0.z-p0.y)*mz1
                 + fabsf(p0.w-p0.z)*mz2 + fabsf(p4  -p0.w)*mz3;

        // H direction (reference dy)
        const float ehx = ph.x - th.x, ehy = ph.y - th.y,
                    ehz = ph.z - th.z, ehw = ph.w - th.w;
        acc[8]  += fabsf(ehx-e0x)*my0 + fabsf(ehy-e0y)*my1
                 + fabsf(ehz-e0z)*my2 + fabsf(ehw-e0w)*my3;
        acc[11] += fabsf(ph.x-p0.x)*my0 + fabsf(ph.y-p0.y)*my1
                 + fabsf(ph.z-p0.z)*my2 + fabsf(ph.w-p0.w)*my3;

        // D direction (reference dx)
        const float edx = pd.x - td.x, edy = pd.y - td.y,
                    edz = pd.z - td.z, edw = pd.w - td.w;
        acc[7]  += fabsf(edx-e0x)*mx0 + fabsf(edy-e0y)*mx1
                 + fabsf(edz-e0z)*mx2 + fabsf(edw-e0w)*mx3;
        acc[10] += fabsf(pd.x-p0.x)*mx0 + fabsf(pd.y-p0.y)*mx1
                 + fabsf(pd.z-p0.z)*mx2 + fabsf(pd.w-p0.w)*mx3;
    }

    // wave (64) shuffle reduce -> LDS -> padded per-block row [block][16]
    const int lane = threadIdx.x & 63;
    const int wave = threadIdx.x >> 6;
    __shared__ float red[4][NACC];
#pragma unroll
    for (int k = 0; k < NACC; ++k) {
        float v = acc[k];
        for (int o = 32; o > 0; o >>= 1) v += __shfl_down(v, o, 64);
        if (lane == 0) red[wave][k] = v;
    }
    __syncthreads();
    if (threadIdx.x < NPAD) {
        const int k = threadIdx.x;
        const float v = (k < NACC)
            ? red[0][k] + red[1][k] + red[2][k] + red[3][k] : 0.f;
        partials[blockIdx.x * NPAD + k] = v;  // d_ws is poisoned: write all 16
    }
}

__global__ __launch_bounds__(1024) void loss_final(
    const float* __restrict__ partials, float* __restrict__ out)
{
    // 1024 threads; thread t owns blocks t, t+1024, t+2048, t+3072.
    // 16 independent float4 loads per thread -> latency fully overlapped.
    float4 a0 = make_float4(0,0,0,0), a1 = a0, a2 = a0, a3 = a0;
#pragma unroll
    for (int i = 0; i < 4; ++i) {
        const float* row = partials + (threadIdx.x + (i << 10)) * NPAD;
        const float4 r0 = ld4(row);     const float4 r1 = ld4(row + 4);
        const float4 r2 = ld4(row + 8); const float4 r3 = ld4(row + 12);
        a0.x += r0.x; a0.y += r0.y; a0.z += r0.z; a0.w += r0.w;
        a1.x += r1.x; a1.y += r1.y; a1.z += r1.z; a1.w += r1.w;
        a2.x += r2.x; a2.y += r2.y; a2.z += r2.z; a2.w += r2.w;
        a3.x += r3.x; a3.y += r3.y; a3.z += r3.z; a3.w += r3.w;
    }
    float acc[NPAD] = {a0.x,a0.y,a0.z,a0.w, a1.x,a1.y,a1.z,a1.w,
                       a2.x,a2.y,a2.z,a2.w, a3.x,a3.y,a3.z,a3.w};

    const int lane = threadIdx.x & 63;
    const int wave = threadIdx.x >> 6;
    __shared__ float red[16][NPAD];
#pragma unroll
    for (int k = 0; k < NPAD; ++k) {
        float v = acc[k];
        for (int o = 32; o > 0; o >>= 1) v += __shfl_down(v, o, 64);
        if (lane == 0) red[wave][k] = v;
    }
    __syncthreads();
    if (threadIdx.x == 0) {
        float a[NACC];
#pragma unroll
        for (int k = 0; k < NACC; ++k) {
            float v = 0.f;
#pragma unroll
            for (int wv = 0; wv < 16; ++wv) v += red[wv][k];
            a[k] = v;
        }
        const float EPS = 1e-8f;
        const float M = a[0], Mx = a[1], My = a[2], Mz = a[3];
        const float dm = 3.f * M + EPS;
        float loss = (a[4] + a[5]) / dm;  // W_MAE=1, W_MSE=1
        loss += 0.1f   * (a[7] / (3.f*Mx + EPS) + a[8] / (3.f*My + EPS)
                        + a[9] / (3.f*Mz + EPS));
        loss += 0.002f * (a[10] / (3.f*Mx + EPS) + a[11] / (3.f*My + EPS)
                        + a[12] / (3.f*Mz + EPS));
        const float inv = 4194304.f - M;  // B*D*H*W - M
        loss += 0.15f * a[6] / (3.f * inv + EPS);
        out[0] = loss;
    }
}

extern "C" void kernel_launch(void* const* d_in, const int* in_sizes, int n_in,
                              void* d_out, int out_size, void* d_ws, size_t ws_size,
                              hipStream_t stream) {
    const float* pred   = (const float*)d_in[0];
    const float* target = (const float*)d_in[1];
    const float* mask   = (const float*)d_in[2];
    float* out      = (float*)d_out;
    float* partials = (float*)d_ws;  // NBLOCKS * NPAD floats = 256 KiB

    loss_main<<<NBLOCKS, 256, 0, stream>>>(pred, target, mask, partials);
    loss_final<<<1, 1024, 0, stream>>>(partials, out);
}